// Round 3
// baseline (64.327 us; speedup 1.0000x reference)
//
#include <hip/hip_runtime.h>

#define D_DIM 4096
#define H_DIM 4096
#define HB 8                // rows (h) per block
#define BLK (HB * 64)       // 512 threads = 8 waves, one per row
#define IB 1024             // columns per tile
#define NSEG (IB / 256)     // 4 float4-segments per lane per tile
#define SP (IB + 4)         // padded LDS stride
#define NT (D_DIM / IB)     // 4 tiles
#define NBLK (H_DIM / HB)   // 512 blocks -> 2 blocks/CU (independent barrier domains)

__device__ __forceinline__ float fast_sigmoid(float a) {
    return __builtin_amdgcn_rcpf(1.0f + __expf(-a));
}

// Grid: NBLK x 512 threads (8 waves). Wave wv owns row h0+wv's prefix scan.
// 2 blocks/CU so one block's compute/barrier overlaps the other's memory burst.
template <bool ATOMIC>
__global__ __launch_bounds__(BLK, 4) void nade_main_kernel(
    const float* __restrict__ x,
    const float* __restrict__ w,
    const float* __restrict__ v,
    const float* __restrict__ c,
    float* __restrict__ part)
{
    __shared__ float S[HB][SP];   // 8 x 1028 x 4B = 32.9 KB -> 2 blocks/CU

    const int tid  = threadIdx.x;
    const int wv   = tid >> 6;
    const int lane = tid & 63;
    const int h0   = blockIdx.x * HB;
    const int h    = h0 + wv;
    const float* wrow = w + (size_t)h * D_DIM;

    float carry = c[h];

    float4 wp[NSEG], wn[NSEG];
    float4 vp[2][2], vn[2][2];    // [col-group][k]: v[i, h0..h0+7], 32B contiguous

    auto load_w = [&](int t, float4* dst) {
        const float* p = wrow + t * IB + 4 * lane;
        #pragma unroll
        for (int s = 0; s < NSEG; ++s)
            dst[s] = *reinterpret_cast<const float4*>(p + s * 256);
    };
    auto load_v = [&](int t, float4 dst[2][2]) {
        #pragma unroll
        for (int g = 0; g < 2; ++g) {
            const int i = t * IB + g * BLK + tid;
            const float* p = v + (size_t)i * H_DIM + h0;
            dst[g][0] = *reinterpret_cast<const float4*>(p);
            dst[g][1] = *reinterpret_cast<const float4*>(p + 4);
        }
    };

    load_w(0, wp);
    load_v(0, vp);

    for (int t = 0; t < NT; ++t) {
        // ---- scan phase: 1024 columns, 4 interleaved 64-lane scans ----
        float4 xp[NSEG];
        {
            const float* p = x + t * IB + 4 * lane;
            #pragma unroll
            for (int s = 0; s < NSEG; ++s)
                xp[s] = *reinterpret_cast<const float4*>(p + s * 256);
        }
        float pr[NSEG][4], sum4[NSEG], incl[NSEG];
        #pragma unroll
        for (int s = 0; s < NSEG; ++s) {
            pr[s][0] = wp[s].x * xp[s].x;
            pr[s][1] = wp[s].y * xp[s].y;
            pr[s][2] = wp[s].z * xp[s].z;
            pr[s][3] = wp[s].w * xp[s].w;
            sum4[s] = pr[s][0] + pr[s][1] + pr[s][2] + pr[s][3];
            incl[s] = sum4[s];
        }
        #pragma unroll
        for (int off = 1; off < 64; off <<= 1) {
            #pragma unroll
            for (int s = 0; s < NSEG; ++s) {
                float tv = __shfl_up(incl[s], off, 64);
                incl[s] += (lane >= off) ? tv : 0.0f;
            }
        }
        float base = carry;
        #pragma unroll
        for (int s = 0; s < NSEG; ++s) {
            float tot = __shfl(incl[s], 63, 64);
            float a0 = base + incl[s] - sum4[s];   // exclusive prefix + carry
            float a1 = a0 + pr[s][0];
            float a2 = a1 + pr[s][1];
            float a3 = a2 + pr[s][2];
            float4 sv;
            sv.x = fast_sigmoid(a0);
            sv.y = fast_sigmoid(a1);
            sv.z = fast_sigmoid(a2);
            sv.w = fast_sigmoid(a3);
            *reinterpret_cast<float4*>(&S[wv][s * 256 + 4 * lane]) = sv;
            base += tot;
        }
        carry = base;

        // prefetch BOTH next-tile streams before the barrier: the burst spans
        // barrier + reduce + next scan-compute, keeping HBM continuously busy
        if (t + 1 < NT) { load_w(t + 1, wn); load_v(t + 1, vn); }
        __syncthreads();

        // ---- reduce phase: thread owns 2 columns, dots v[i, h0:h0+8] with S ----
        #pragma unroll
        for (int g = 0; g < 2; ++g) {
            const int il = g * BLK + tid;
            float acc = vp[g][0].x * S[0][il] + vp[g][0].y * S[1][il]
                      + vp[g][0].z * S[2][il] + vp[g][0].w * S[3][il]
                      + vp[g][1].x * S[4][il] + vp[g][1].y * S[5][il]
                      + vp[g][1].z * S[6][il] + vp[g][1].w * S[7][il];
            const int i = t * IB + il;
            if (ATOMIC) atomicAdd(&part[i], acc);
            else        part[(size_t)blockIdx.x * D_DIM + i] = acc;
        }
        __syncthreads();   // S reads done before next scan overwrites

        #pragma unroll
        for (int s = 0; s < NSEG; ++s) wp[s] = wn[s];
        #pragma unroll
        for (int g = 0; g < 2; ++g) { vp[g][0] = vn[g][0]; vp[g][1] = vn[g][1]; }
    }
}

// Grid: D/64 blocks x 1024 threads. Sums the [NBLK][D] partial matrix (coalesced).
__global__ __launch_bounds__(1024, 1) void nade_reduce_kernel(
    const float* __restrict__ part,
    const float* __restrict__ b,
    float* __restrict__ out)
{
    __shared__ float red[16][64];
    const int tid = threadIdx.x;
    const int bg  = tid >> 6;      // wave id 0..15
    const int il  = tid & 63;
    const int i   = blockIdx.x * 64 + il;
    float s = 0.0f;
    #pragma unroll
    for (int j = 0; j < NBLK / 16; ++j)
        s += part[(size_t)(bg * (NBLK / 16) + j) * D_DIM + i];
    red[bg][il] = s;
    __syncthreads();
    if (tid < 64) {
        float t = b[blockIdx.x * 64 + tid];
        #pragma unroll
        for (int j = 0; j < 16; ++j) t += red[j][tid];
        out[blockIdx.x * 64 + tid] = fast_sigmoid(t);
    }
}

__global__ __launch_bounds__(256, 1) void nade_final_atomic(
    const float* __restrict__ logits,
    const float* __restrict__ b,
    float* __restrict__ out)
{
    const int i = blockIdx.x * 256 + threadIdx.x;
    out[i] = fast_sigmoid(logits[i] + b[i]);
}

extern "C" void kernel_launch(void* const* d_in, const int* in_sizes, int n_in,
                              void* d_out, int out_size, void* d_ws, size_t ws_size,
                              hipStream_t stream)
{
    const float* x = (const float*)d_in[0];
    const float* w = (const float*)d_in[1];
    const float* b = (const float*)d_in[2];
    const float* v = (const float*)d_in[3];
    const float* c = (const float*)d_in[4];
    float* out = (float*)d_out;
    float* ws  = (float*)d_ws;

    const size_t need = (size_t)NBLK * D_DIM * sizeof(float);
    if (ws_size >= need) {
        nade_main_kernel<false><<<NBLK, BLK, 0, stream>>>(x, w, v, c, ws);
        nade_reduce_kernel<<<D_DIM / 64, 1024, 0, stream>>>(ws, b, out);
    } else {
        hipMemsetAsync(d_ws, 0, D_DIM * sizeof(float), stream);
        nade_main_kernel<true><<<NBLK, BLK, 0, stream>>>(x, w, v, c, ws);
        nade_final_atomic<<<D_DIM / 256, 256, 0, stream>>>(ws, b, out);
    }
}

// Round 4
// 45.250 us; speedup vs baseline: 1.4216x; 1.4216x over previous
//
#include <hip/hip_runtime.h>

#define D_DIM 4096
#define H_DIM 4096
#define HB 16               // rows (h) per block; 64B v-line granularity
#define BLK 1024            // 16 waves; wave wv owns row h0+wv
#define IB 512              // columns per phase
#define SP (IB + 4)         // padded LDS stride
#define NT (D_DIM / IB)     // 8 phases
#define NBLK (H_DIM / HB)   // 256 blocks

__device__ __forceinline__ float fast_sigmoid(float a) {
    return __builtin_amdgcn_rcpf(1.0f + __expf(-a));
}

// Schedule per phase k (one barrier per phase, S double-buffered):
//   A: issue w(k+1), v(k)  -- pinned at top via sched_barrier(0)
//   B: scan(k) with w(k) (issued phase k-1) -> S[k&1]
//   C: reduce(k-1) with v(k-1) (issued phase k-1) and S[(k-1)&1]
//   D: rotate buffers; __syncthreads()
// Loads thus have a full phase of scan+reduce compute to hide under.
template <bool ATOMIC>
__global__ __launch_bounds__(BLK, 4) void nade_main_kernel(
    const float* __restrict__ x,
    const float* __restrict__ w,
    const float* __restrict__ v,
    const float* __restrict__ c,
    float* __restrict__ part)
{
    __shared__ float S[2][HB][SP];   // 2 x 16 x 516 x 4B = 66 KB

    const int tid  = threadIdx.x;
    const int wv   = tid >> 6;
    const int lane = tid & 63;
    const int h0   = blockIdx.x * HB;
    const int il   = tid >> 1;   // reduce: column in tile (0..511)
    const int hh   = tid & 1;    // reduce: h-half (pairs share one 64B v line)

    const float* wrow = w + (size_t)(h0 + wv) * D_DIM;
    float carry = c[h0 + wv];

    float4 wc0, wc1, wn0, wn1;   // w cur/next: 2 segs of 4 cols per lane
    float4 vc0, vc1, vn0, vn1;   // v cur/next: v[i, h0+8*hh .. +8]

    auto wptr = [&](int t, int s) { return wrow + t * IB + s * 256 + 4 * lane; };
    auto vptr = [&](int t) {
        return v + (size_t)(t * IB + il) * H_DIM + h0 + 8 * hh;
    };

    // prologue: issue w(0)
    wc0 = *reinterpret_cast<const float4*>(wptr(0, 0));
    wc1 = *reinterpret_cast<const float4*>(wptr(0, 1));

    #pragma unroll
    for (int k = 0; k < NT; ++k) {
        const int cb = k & 1;

        // ---- A: issue next-phase loads (pinned above compute) ----
        if (k + 1 < NT) {
            wn0 = *reinterpret_cast<const float4*>(wptr(k + 1, 0));
            wn1 = *reinterpret_cast<const float4*>(wptr(k + 1, 1));
        }
        {
            const float* pv = vptr(k);
            vn0 = *reinterpret_cast<const float4*>(pv);
            vn1 = *reinterpret_cast<const float4*>(pv + 4);
        }
        __builtin_amdgcn_sched_barrier(0);

        // ---- B: scan(k): 512 cols, 2 interleaved 64-lane segment scans ----
        float4 xa = *reinterpret_cast<const float4*>(x + k * IB + 4 * lane);
        float4 xb = *reinterpret_cast<const float4*>(x + k * IB + 256 + 4 * lane);
        float pa[4], pb[4];
        pa[0] = wc0.x * xa.x; pa[1] = wc0.y * xa.y; pa[2] = wc0.z * xa.z; pa[3] = wc0.w * xa.w;
        pb[0] = wc1.x * xb.x; pb[1] = wc1.y * xb.y; pb[2] = wc1.z * xb.z; pb[3] = wc1.w * xb.w;
        float s4a = pa[0] + pa[1] + pa[2] + pa[3];
        float s4b = pb[0] + pb[1] + pb[2] + pb[3];
        float ia = s4a, ib = s4b;
        #pragma unroll
        for (int off = 1; off < 64; off <<= 1) {
            float ta = __shfl_up(ia, off, 64);
            float tb = __shfl_up(ib, off, 64);
            ia += (lane >= off) ? ta : 0.0f;
            ib += (lane >= off) ? tb : 0.0f;
        }
        float tot_a = __shfl(ia, 63, 64);
        float tot_b = __shfl(ib, 63, 64);
        {
            float ea = carry + ia - s4a;            // exclusive prefix, seg a
            float a1 = ea + pa[0], a2 = a1 + pa[1], a3 = a2 + pa[2];
            float4 sv;
            sv.x = fast_sigmoid(ea); sv.y = fast_sigmoid(a1);
            sv.z = fast_sigmoid(a2); sv.w = fast_sigmoid(a3);
            *reinterpret_cast<float4*>(&S[cb][wv][4 * lane]) = sv;
        }
        {
            float base_b = carry + tot_a;
            float eb = base_b + ib - s4b;           // exclusive prefix, seg b
            float b1 = eb + pb[0], b2 = b1 + pb[1], b3 = b2 + pb[2];
            float4 sv;
            sv.x = fast_sigmoid(eb); sv.y = fast_sigmoid(b1);
            sv.z = fast_sigmoid(b2); sv.w = fast_sigmoid(b3);
            *reinterpret_cast<float4*>(&S[cb][wv][256 + 4 * lane]) = sv;
            carry = base_b + tot_b;
        }

        // ---- C: reduce(k-1): pair (il,hh) dots 8 h's; shfl_xor combines ----
        if (k > 0) {
            const int rb = cb ^ 1;
            const float* Sc = &S[rb][8 * hh][0];
            float acc = vc0.x * Sc[0 * SP + il] + vc0.y * Sc[1 * SP + il]
                      + vc0.z * Sc[2 * SP + il] + vc0.w * Sc[3 * SP + il]
                      + vc1.x * Sc[4 * SP + il] + vc1.y * Sc[5 * SP + il]
                      + vc1.z * Sc[6 * SP + il] + vc1.w * Sc[7 * SP + il];
            acc += __shfl_xor(acc, 1, 64);
            if (hh == 0) {
                const int i = (k - 1) * IB + il;
                if (ATOMIC) atomicAdd(&part[i], acc);
                else        part[(size_t)blockIdx.x * D_DIM + i] = acc;
            }
        }

        // ---- D: rotate ----
        wc0 = wn0; wc1 = wn1; vc0 = vn0; vc1 = vn1;
        __syncthreads();
    }

    // epilogue: reduce(NT-1)
    {
        const int rb = (NT - 1) & 1;
        const float* Sc = &S[rb][8 * hh][0];
        float acc = vc0.x * Sc[0 * SP + il] + vc0.y * Sc[1 * SP + il]
                  + vc0.z * Sc[2 * SP + il] + vc0.w * Sc[3 * SP + il]
                  + vc1.x * Sc[4 * SP + il] + vc1.y * Sc[5 * SP + il]
                  + vc1.z * Sc[6 * SP + il] + vc1.w * Sc[7 * SP + il];
        acc += __shfl_xor(acc, 1, 64);
        if (hh == 0) {
            const int i = (NT - 1) * IB + il;
            if (ATOMIC) atomicAdd(&part[i], acc);
            else        part[(size_t)blockIdx.x * D_DIM + i] = acc;
        }
    }
}

// Grid: D/64 blocks x 1024 threads. Sums the [NBLK][D] partial matrix (coalesced).
__global__ __launch_bounds__(1024, 1) void nade_reduce_kernel(
    const float* __restrict__ part,
    const float* __restrict__ b,
    float* __restrict__ out)
{
    __shared__ float red[16][64];
    const int tid = threadIdx.x;
    const int bg  = tid >> 6;      // wave id 0..15
    const int il  = tid & 63;
    const int i   = blockIdx.x * 64 + il;
    float s = 0.0f;
    #pragma unroll
    for (int j = 0; j < NBLK / 16; ++j)
        s += part[(size_t)(bg * (NBLK / 16) + j) * D_DIM + i];
    red[bg][il] = s;
    __syncthreads();
    if (tid < 64) {
        float t = b[blockIdx.x * 64 + tid];
        #pragma unroll
        for (int j = 0; j < 16; ++j) t += red[j][tid];
        out[blockIdx.x * 64 + tid] = fast_sigmoid(t);
    }
}

__global__ __launch_bounds__(256, 1) void nade_final_atomic(
    const float* __restrict__ logits,
    const float* __restrict__ b,
    float* __restrict__ out)
{
    const int i = blockIdx.x * 256 + threadIdx.x;
    out[i] = fast_sigmoid(logits[i] + b[i]);
}

extern "C" void kernel_launch(void* const* d_in, const int* in_sizes, int n_in,
                              void* d_out, int out_size, void* d_ws, size_t ws_size,
                              hipStream_t stream)
{
    const float* x = (const float*)d_in[0];
    const float* w = (const float*)d_in[1];
    const float* b = (const float*)d_in[2];
    const float* v = (const float*)d_in[3];
    const float* c = (const float*)d_in[4];
    float* out = (float*)d_out;
    float* ws  = (float*)d_ws;

    const size_t need = (size_t)NBLK * D_DIM * sizeof(float);
    if (ws_size >= need) {
        nade_main_kernel<false><<<NBLK, BLK, 0, stream>>>(x, w, v, c, ws);
        nade_reduce_kernel<<<D_DIM / 64, 1024, 0, stream>>>(ws, b, out);
    } else {
        hipMemsetAsync(d_ws, 0, D_DIM * sizeof(float), stream);
        nade_main_kernel<true><<<NBLK, BLK, 0, stream>>>(x, w, v, c, ws);
        nade_final_atomic<<<D_DIM / 256, 256, 0, stream>>>(ws, b, out);
    }
}